// Round 2
// baseline (67088.757 us; speedup 1.0000x reference)
//
#include <hip/hip_runtime.h>
#include <math.h>

// Problem constants
#define BB   64
#define SS   512
#define EE   256
#define HH   512
#define HD   1024
#define TT   9
#define MM   (BB*SS)      // 32768 rows
#define NG   4096         // 2 dirs * 4 gates * H

// ---------------------------------------------------------------------------
// Grid-stride zero-fill (replaces hipMemsetAsync; trivially graph-safe).
// ---------------------------------------------------------------------------
__global__ void zero_kernel(float* __restrict__ p, int n)
{
    int i = blockIdx.x * blockDim.x + threadIdx.x;
    int stride = gridDim.x * blockDim.x;
    for (; i < n; i += stride) p[i] = 0.f;
}

// ---------------------------------------------------------------------------
// GEMM: C[M,4096] = A[M,K] @ W[4096,K]^T + bias0 + bias1   (big path only)
// GATHER=true: A row m is emb[ids[m]] (embedding fused, K=256)
// Tile 64x64, BK=32, 256 threads, 4x4 micro-tile.
// ---------------------------------------------------------------------------
template<bool GATHER>
__global__ __launch_bounds__(256)
void gemm_bias_kernel(const float* __restrict__ A, const int* __restrict__ ids,
                      const float* __restrict__ emb,
                      const float* __restrict__ W,
                      const float* __restrict__ bias0, const float* __restrict__ bias1,
                      float* __restrict__ C, int K)
{
    __shared__ float As[32][68];   // [k][m]; row stride 68 floats = 272 B (16B-aligned)
    __shared__ float Bs[32][68];   // [k][n]
    const int tid = threadIdx.x;
    const int m0 = blockIdx.y * 64, n0 = blockIdx.x * 64;
    const int ty = tid >> 4, tx = tid & 15;
    const int rl = tid >> 2;            // 0..63 (row within tile)
    const int kl = (tid & 3) * 8;       // 0,8,16,24

    const float* Arow;
    if (GATHER) Arow = emb + (size_t)ids[m0 + rl] * K;
    else        Arow = A   + (size_t)(m0 + rl) * K;
    const float* Wrow = W + (size_t)(n0 + rl) * K;

    float acc[4][4] = {};
    for (int kc = 0; kc < K; kc += 32) {
        float4 a0 = *(const float4*)(Arow + kc + kl);
        float4 a1 = *(const float4*)(Arow + kc + kl + 4);
        float4 b0 = *(const float4*)(Wrow + kc + kl);
        float4 b1 = *(const float4*)(Wrow + kc + kl + 4);
        __syncthreads();
        As[kl+0][rl]=a0.x; As[kl+1][rl]=a0.y; As[kl+2][rl]=a0.z; As[kl+3][rl]=a0.w;
        As[kl+4][rl]=a1.x; As[kl+5][rl]=a1.y; As[kl+6][rl]=a1.z; As[kl+7][rl]=a1.w;
        Bs[kl+0][rl]=b0.x; Bs[kl+1][rl]=b0.y; Bs[kl+2][rl]=b0.z; Bs[kl+3][rl]=b0.w;
        Bs[kl+4][rl]=b1.x; Bs[kl+5][rl]=b1.y; Bs[kl+6][rl]=b1.z; Bs[kl+7][rl]=b1.w;
        __syncthreads();
        #pragma unroll
        for (int k = 0; k < 32; k++) {
            float4 av = *(const float4*)&As[k][ty*4];
            float4 bv = *(const float4*)&Bs[k][tx*4];
            float a_[4] = {av.x, av.y, av.z, av.w};
            float b_[4] = {bv.x, bv.y, bv.z, bv.w};
            #pragma unroll
            for (int i = 0; i < 4; i++)
                #pragma unroll
                for (int j = 0; j < 4; j++)
                    acc[i][j] += a_[i] * b_[j];
        }
    }
    #pragma unroll
    for (int i = 0; i < 4; i++) {
        const int m = m0 + ty*4 + i;
        const int n = n0 + tx*4;
        float4 o;
        o.x = acc[i][0] + bias0[n+0] + bias1[n+0];
        o.y = acc[i][1] + bias0[n+1] + bias1[n+1];
        o.z = acc[i][2] + bias0[n+2] + bias1[n+2];
        o.w = acc[i][3] + bias0[n+3] + bias1[n+3];
        *(float4*)(C + (size_t)m * NG + n) = o;
    }
}

// ---------------------------------------------------------------------------
// One LSTM time step, both directions, xg precomputed (big path).
// Grid 256 blocks: blockIdx>>7 = dir, (blockIdx&127)*4 = j0.
// Thread (b=tid&63, jl=tid>>6) computes 4 gate dots (K=512) + gates.
// ---------------------------------------------------------------------------
__global__ __launch_bounds__(256)
void lstm_step_kernel(const float* __restrict__ xg, const float* __restrict__ w_hh,
                      const float* __restrict__ h_in, float* __restrict__ h_out,
                      float* __restrict__ c_state, float* __restrict__ out,
                      int t_fwd)
{
    __shared__ float Hs[64][132];
    __shared__ float Ws[16][128];
    const int bid = blockIdx.x;
    const int d   = bid >> 7;
    const int j0  = (bid & 127) * 4;
    const int tid = threadIdx.x;
    const int b   = tid & 63;
    const int jl  = tid >> 6;           // 0..3
    const int j   = j0 + jl;
    const int t   = d ? (SS - 1 - t_fwd) : t_fwd;
    const float* hbase = h_in + d * (BB*HH);
    const float* wbase = w_hh + (size_t)d * (2048*512);

    float acc[4] = {0.f, 0.f, 0.f, 0.f};
    for (int kc = 0; kc < 512; kc += 128) {
        __syncthreads();
        #pragma unroll
        for (int r = 0; r < 8; r++) {               // stage h chunk 64x128
            int f4 = tid + r*256;
            int row = f4 >> 5;
            int c4  = (f4 & 31) * 4;
            *(float4*)&Hs[row][c4] = *(const float4*)(hbase + row*HH + kc + c4);
        }
        #pragma unroll
        for (int r = 0; r < 2; r++) {               // stage 16 weight rows x128
            int f4 = tid + r*256;
            int rr = f4 >> 5;                       // 0..15 = q*4 + jj
            int c4 = (f4 & 31) * 4;
            int q = rr >> 2, jj = rr & 3;
            *(float4*)&Ws[rr][c4] =
                *(const float4*)(wbase + (size_t)(q*512 + j0 + jj)*512 + kc + c4);
        }
        __syncthreads();
        #pragma unroll
        for (int kk = 0; kk < 128; kk += 4) {
            float4 hv = *(const float4*)&Hs[b][kk];
            #pragma unroll
            for (int q = 0; q < 4; q++) {
                float4 wv = *(const float4*)&Ws[q*4 + jl][kk];  // wave-uniform broadcast
                acc[q] += hv.x*wv.x + hv.y*wv.y + hv.z*wv.z + hv.w*wv.w;
            }
        }
    }
    const float* xr = xg + ((size_t)(b*SS + t)) * NG + d*2048;
    float gi = xr[j]        + acc[0];
    float gf = xr[512  + j] + acc[1];
    float gg = xr[1024 + j] + acc[2];
    float go = xr[1536 + j] + acc[3];
    float i_ = 1.f / (1.f + expf(-gi));
    float f_ = 1.f / (1.f + expf(-gf));
    float g_ = tanhf(gg);
    float o_ = 1.f / (1.f + expf(-go));
    const int sidx = d*(BB*HH) + b*HH + j;
    float cn = f_ * c_state[sidx] + i_ * g_;
    float hn = o_ * tanhf(cn);
    c_state[sidx] = cn;
    h_out[sidx]   = hn;
    out[((size_t)(b*SS + t)) * HD + d*HH + j] = hn;
}

// ---------------------------------------------------------------------------
// Fused LSTM step (small path): computes x@W_ih^T inline (no xg buffer).
// KX = x feature dim; GATHER: x row b = emb[ids[b*S+t]]; else x = xsrc[b,t,:].
// FUSE_LOGITS: instead of writing h to out[b,t,:], accumulate partial
// logits (h . cls_w) into out via block-reduce + atomicAdd (no h1out buffer).
// ---------------------------------------------------------------------------
template<int KX, bool GATHER, bool FUSE_LOGITS>
__global__ __launch_bounds__(256)
void lstm_fused_step(const float* __restrict__ xsrc, const int* __restrict__ ids,
                     const float* __restrict__ w_ih, const float* __restrict__ w_hh,
                     const float* __restrict__ b_ih, const float* __restrict__ b_hh,
                     const float* __restrict__ h_in, float* __restrict__ h_out,
                     float* __restrict__ c_state, float* __restrict__ out,
                     const float* __restrict__ cls_w, int t_fwd)
{
    __shared__ float Hs[64][132];
    __shared__ float Ws[16][128];
    __shared__ float Red[FUSE_LOGITS ? 4 : 1][64][10];
    const int bid = blockIdx.x;
    const int d   = bid >> 7;
    const int j0  = (bid & 127) * 4;
    const int tid = threadIdx.x;
    const int b   = tid & 63;
    const int jl  = tid >> 6;
    const int j   = j0 + jl;
    const int t   = d ? (SS - 1 - t_fwd) : t_fwd;

    float acc[4];
    #pragma unroll
    for (int q = 0; q < 4; q++) {
        int g = d*2048 + q*512 + j;
        acc[q] = b_ih[g] + b_hh[g];
    }

    // ---- x-projection: K = KX
    const float* wx = w_ih + (size_t)d * 2048 * KX;
    for (int kc = 0; kc < KX; kc += 128) {
        __syncthreads();
        #pragma unroll
        for (int r = 0; r < 8; r++) {
            int f4  = tid + r*256;
            int row = f4 >> 5;
            int c4  = (f4 & 31) * 4;
            const float* xrow;
            if (GATHER) xrow = xsrc + (size_t)ids[row*SS + t] * KX;
            else        xrow = xsrc + ((size_t)row * SS + t) * KX;
            *(float4*)&Hs[row][c4] = *(const float4*)(xrow + kc + c4);
        }
        #pragma unroll
        for (int r = 0; r < 2; r++) {
            int f4 = tid + r*256;
            int rr = f4 >> 5;
            int c4 = (f4 & 31) * 4;
            int q = rr >> 2, jj = rr & 3;
            *(float4*)&Ws[rr][c4] =
                *(const float4*)(wx + (size_t)(q*512 + j0 + jj)*KX + kc + c4);
        }
        __syncthreads();
        #pragma unroll
        for (int kk = 0; kk < 128; kk += 4) {
            float4 hv = *(const float4*)&Hs[b][kk];
            #pragma unroll
            for (int q = 0; q < 4; q++) {
                float4 wv = *(const float4*)&Ws[q*4 + jl][kk];
                acc[q] += hv.x*wv.x + hv.y*wv.y + hv.z*wv.z + hv.w*wv.w;
            }
        }
    }

    // ---- h-recurrence: K = 512
    const float* hbase = h_in + d * (BB*HH);
    const float* wh = w_hh + (size_t)d * 2048 * 512;
    for (int kc = 0; kc < 512; kc += 128) {
        __syncthreads();
        #pragma unroll
        for (int r = 0; r < 8; r++) {
            int f4  = tid + r*256;
            int row = f4 >> 5;
            int c4  = (f4 & 31) * 4;
            *(float4*)&Hs[row][c4] = *(const float4*)(hbase + row*HH + kc + c4);
        }
        #pragma unroll
        for (int r = 0; r < 2; r++) {
            int f4 = tid + r*256;
            int rr = f4 >> 5;
            int c4 = (f4 & 31) * 4;
            int q = rr >> 2, jj = rr & 3;
            *(float4*)&Ws[rr][c4] =
                *(const float4*)(wh + (size_t)(q*512 + j0 + jj)*512 + kc + c4);
        }
        __syncthreads();
        #pragma unroll
        for (int kk = 0; kk < 128; kk += 4) {
            float4 hv = *(const float4*)&Hs[b][kk];
            #pragma unroll
            for (int q = 0; q < 4; q++) {
                float4 wv = *(const float4*)&Ws[q*4 + jl][kk];
                acc[q] += hv.x*wv.x + hv.y*wv.y + hv.z*wv.z + hv.w*wv.w;
            }
        }
    }

    float i_ = 1.f / (1.f + expf(-acc[0]));
    float f_ = 1.f / (1.f + expf(-acc[1]));
    float g_ = tanhf(acc[2]);
    float o_ = 1.f / (1.f + expf(-acc[3]));
    const int sidx = d*(BB*HH) + b*HH + j;
    float cn = f_ * c_state[sidx] + i_ * g_;
    float hn = o_ * tanhf(cn);
    c_state[sidx] = cn;
    h_out[sidx]   = hn;

    if (FUSE_LOGITS) {
        #pragma unroll
        for (int n = 0; n < TT; n++)
            Red[jl][b][n] = hn * cls_w[n*HD + d*HH + j];
        __syncthreads();
        if (tid < 64) {
            #pragma unroll
            for (int n = 0; n < TT; n++) {
                float s = Red[0][tid][n] + Red[1][tid][n] + Red[2][tid][n] + Red[3][tid][n];
                atomicAdd(out + ((size_t)tid*SS + t)*TT + n, s);
            }
        }
    } else {
        out[((size_t)(b*SS + t)) * HD + d*HH + j] = hn;
    }
}

// ---------------------------------------------------------------------------
// logits[row, n] = x[row,:] . cls_w[n,:]   (bias added later in CRF kernel)
// ---------------------------------------------------------------------------
__global__ __launch_bounds__(256)
void logits_kernel(const float* __restrict__ x, const float* __restrict__ cls_w,
                   float* __restrict__ out)
{
    __shared__ float Wc[TT * HD];
    const int tid = threadIdx.x;
    for (int i = tid; i < TT*HD; i += 256) Wc[i] = cls_w[i];
    __syncthreads();
    const int lane = tid & 63;
    const int row  = blockIdx.x * 4 + (tid >> 6);
    const float* xr = x + (size_t)row * HD;
    float p[TT] = {};
    for (int k = lane; k < HD; k += 64) {
        float xv = xr[k];
        #pragma unroll
        for (int n = 0; n < TT; n++) p[n] += xv * Wc[n*HD + k];
    }
    #pragma unroll
    for (int n = 0; n < TT; n++) {
        float v = p[n];
        #pragma unroll
        for (int off = 32; off > 0; off >>= 1) v += __shfl_down(v, off);
        if (lane == 0) out[(size_t)row * TT + n] = v;
    }
}

// ---------------------------------------------------------------------------
// CRF viterbi decode + loss per batch row. 1 wave per row. cls_b folded in.
// ---------------------------------------------------------------------------
__global__ __launch_bounds__(64)
void crf_kernel(const float* __restrict__ logits, const int* __restrict__ labels,
                const int* __restrict__ vlens, const float* __restrict__ trans,
                const float* __restrict__ start_t, const float* __restrict__ end_t,
                const float* __restrict__ cls_b,
                float* __restrict__ tags_out, float* __restrict__ llh)
{
    const int b = blockIdx.x;
    const int lane = threadIdx.x;
    const int len = vlens[b];
    const float* em = logits + (size_t)b * (SS*TT);
    const int*  lab = labels + (size_t)b * SS;
    __shared__ unsigned char hist[(SS-1)*TT];

    float cb = (lane < TT) ? cls_b[lane] : 0.f;
    float tcol[TT];
    #pragma unroll
    for (int i = 0; i < TT; i++) tcol[i] = (lane < TT) ? trans[i*TT + lane] : 0.f;
    float score = (lane < TT) ? (start_t[lane] + em[lane] + cb) : 0.f;
    float alpha = score;
    float num = 0.f; int plab = 0;
    if (lane == 0) { plab = lab[0]; num = start_t[plab] + em[plab] + cls_b[plab]; }

    for (int t = 1; t < SS; t++) {
        float emj = (lane < TT) ? (em[t*TT + lane] + cb) : 0.f;
        float sv[TT], av[TT];
        #pragma unroll
        for (int i = 0; i < TT; i++) { sv[i] = __shfl(score, i); av[i] = __shfl(alpha, i); }
        float best = -INFINITY; int bp = 0; float amx = -INFINITY;
        #pragma unroll
        for (int i = 0; i < TT; i++) {
            float c = sv[i] + tcol[i];
            if (c > best) { best = c; bp = i; }     // strict > keeps FIRST max (jnp.argmax)
            amx = fmaxf(amx, av[i] + tcol[i]);
        }
        float se = 0.f;
        #pragma unroll
        for (int i = 0; i < TT; i++) se += expf(av[i] + tcol[i] - amx);
        const bool m = (t < len);
        if (m) { score = best + emj; alpha = amx + logf(se) + emj; }
        if (lane < TT) hist[(t-1)*TT + lane] = (unsigned char)bp;
        if (lane == 0 && m) {
            int lt = lab[t];
            num += em[t*TT + lt] + cls_b[lt] + trans[plab*TT + lt];
            plab = lt;
        }
    }
    float fsc[TT], fal[TT];
    #pragma unroll
    for (int i = 0; i < TT; i++) { fsc[i] = __shfl(score, i); fal[i] = __shfl(alpha, i); }
    __syncthreads();
    if (lane == 0) {
        num += end_t[lab[len-1]];
        int bl = 0; float bv = fsc[0] + end_t[0];
        #pragma unroll
        for (int i = 1; i < TT; i++) {
            float v = fsc[i] + end_t[i];
            if (v > bv) { bv = v; bl = i; }
        }
        float zmx = -INFINITY;
        #pragma unroll
        for (int i = 0; i < TT; i++) zmx = fmaxf(zmx, fal[i] + end_t[i]);
        float zse = 0.f;
        #pragma unroll
        for (int i = 0; i < TT; i++) zse += expf(fal[i] + end_t[i] - zmx);
        llh[b] = num - (zmx + logf(zse));
        int tag = bl;
        tags_out[b*SS + (SS-1)] = (float)tag;
        for (int t = SS-2; t >= 0; t--) {
            if (t + 1 < len) tag = hist[t*TT + tag];
            tags_out[b*SS + t] = (float)tag;
        }
    }
}

__global__ void loss_kernel(const float* __restrict__ llh, float* __restrict__ out)
{
    float v = llh[threadIdx.x];
    #pragma unroll
    for (int off = 32; off > 0; off >>= 1) v += __shfl_down(v, off);
    if (threadIdx.x == 0) out[MM] = -(v / 64.f);
}

// ---------------------------------------------------------------------------
extern "C" void kernel_launch(void* const* d_in, const int* in_sizes, int n_in,
                              void* d_out, int out_size, void* d_ws, size_t ws_size,
                              hipStream_t stream)
{
    const int*   ids     = (const int*)  d_in[0];
    const int*   vlen    = (const int*)  d_in[1];
    const int*   labels  = (const int*)  d_in[2];
    const float* emb     = (const float*)d_in[3];
    const float* w_ih0   = (const float*)d_in[4];
    const float* w_hh0   = (const float*)d_in[5];
    const float* b_ih0   = (const float*)d_in[6];
    const float* b_hh0   = (const float*)d_in[7];
    const float* w_ih1   = (const float*)d_in[8];
    const float* w_hh1   = (const float*)d_in[9];
    const float* b_ih1   = (const float*)d_in[10];
    const float* b_hh1   = (const float*)d_in[11];
    const float* cls_w   = (const float*)d_in[12];
    const float* cls_b   = (const float*)d_in[13];
    const float* trans   = (const float*)d_in[14];
    const float* start_t = (const float*)d_in[15];
    const float* end_t   = (const float*)d_in[16];

    // Workspace layout (floats), small buffers first so both paths share it:
    //   [logits MM*9 | llh 64 | hb0 | cst | hb1 | h0out MM*1024 | xg MM*4096]
    float* ws     = (float*)d_ws;
    float* logits = ws;
    float* llh    = logits + (size_t)MM * TT;
    float* hb0    = llh    + 64;
    float* cst    = hb0    + 2*BB*HH;
    float* hb1    = cst    + 2*BB*HH;
    float* h0out  = hb1    + 2*BB*HH;
    float* xg     = h0out  + (size_t)MM * HD;

    const size_t small_need = ((size_t)MM*TT + 64 + 3*(2*BB*HH) + (size_t)MM*HD) * sizeof(float);
    const size_t big_need   = small_need + (size_t)MM * NG * sizeof(float);
    const bool   big        = (ws_size >= big_need);

    const int nzero1 = MM*TT + 64 + 2*(2*BB*HH);   // logits, llh, hb0, cst
    const int nzero2 = 2*(2*BB*HH);                // hb0, cst

    zero_kernel<<<512, 256, 0, stream>>>(logits, nzero1);

    if (big) {
        dim3 ggemm(NG/64, MM/64);
        // Layer 0: fused embed-gather + input projection (biases folded in)
        gemm_bias_kernel<true><<<ggemm, 256, 0, stream>>>(
            nullptr, ids, emb, w_ih0, b_ih0, b_hh0, xg, EE);
        for (int s = 0; s < SS; s++) {
            float* hin  = (s & 1) ? hb1 : hb0;
            float* hout = (s & 1) ? hb0 : hb1;
            lstm_step_kernel<<<256, 256, 0, stream>>>(xg, w_hh0, hin, hout, cst, h0out, s);
        }
        // Layer 1 input projection; afterwards h0out is dead -> h1 aliases it
        gemm_bias_kernel<false><<<ggemm, 256, 0, stream>>>(
            h0out, nullptr, nullptr, w_ih1, b_ih1, b_hh1, xg, HD);
        zero_kernel<<<512, 256, 0, stream>>>(hb0, nzero2);
        float* h1out = h0out;
        for (int s = 0; s < SS; s++) {
            float* hin  = (s & 1) ? hb1 : hb0;
            float* hout = (s & 1) ? hb0 : hb1;
            lstm_step_kernel<<<256, 256, 0, stream>>>(xg, w_hh1, hin, hout, cst, h1out, s);
        }
        logits_kernel<<<MM/4, 256, 0, stream>>>(h1out, cls_w, logits);
    } else {
        // Small path: fused input projection, no xg; layer-1 fuses classifier
        // into per-step atomic logits accumulation, no h1out.
        for (int s = 0; s < SS; s++) {
            float* hin  = (s & 1) ? hb1 : hb0;
            float* hout = (s & 1) ? hb0 : hb1;
            lstm_fused_step<EE, true, false><<<256, 256, 0, stream>>>(
                emb, ids, w_ih0, w_hh0, b_ih0, b_hh0, hin, hout, cst, h0out, nullptr, s);
        }
        zero_kernel<<<512, 256, 0, stream>>>(hb0, nzero2);
        for (int s = 0; s < SS; s++) {
            float* hin  = (s & 1) ? hb1 : hb0;
            float* hout = (s & 1) ? hb0 : hb1;
            lstm_fused_step<HD, false, true><<<256, 256, 0, stream>>>(
                h0out, nullptr, w_ih1, w_hh1, b_ih1, b_hh1, hin, hout, cst, logits, cls_w, s);
        }
    }

    crf_kernel<<<BB, 64, 0, stream>>>(logits, labels, vlen, trans, start_t, end_t,
                                      cls_b, (float*)d_out, llh);
    loss_kernel<<<1, 64, 0, stream>>>(llh, (float*)d_out);
}